// Round 1
// baseline (839.912 us; speedup 1.0000x reference)
//
#include <hip/hip_runtime.h>

#define E_TOTAL 1600000
#define N_NODES 100000
#define ND 64
#define ED 32
#define IN_DIM 160
#define HID 128
#define OUTD 64

#define TM 128          // edges per tile
#define H_STRIDE 136    // padded bf16 stride for h tile (row = 272 B, 16B-aligned)

typedef short v8s __attribute__((ext_vector_type(8)));
typedef float v4f __attribute__((ext_vector_type(4)));

__device__ __forceinline__ unsigned short f2bf(float f) {
    union { float f; unsigned u; } v; v.f = f;
    unsigned u = v.u;
    u += 0x7FFFu + ((u >> 16) & 1u);   // RNE
    return (unsigned short)(u >> 16);
}

__device__ __forceinline__ v8s cvt8v(v4f f0, v4f f1) {
    v8s r;
#pragma unroll
    for (int t = 0; t < 4; ++t) {
        r[t]     = (short)f2bf(f0[t]);
        r[t + 4] = (short)f2bf(f1[t]);
    }
    return r;
}

// ---- prep: x -> bf16 (row-major, 128 B/node) ----
__global__ void prep_x(const float* __restrict__ x, unsigned short* __restrict__ xbf) {
    int i = blockIdx.x * blockDim.x + threadIdx.x;
    if (i < N_NODES * ND) xbf[i] = f2bf(__builtin_nontemporal_load(x + i));
}

// ---- prep: W1/W2 -> bf16 in exact MFMA B-fragment order ----
__global__ void prep_weights(const float* __restrict__ W1, const float* __restrict__ W2,
                             unsigned short* __restrict__ w1f, unsigned short* __restrict__ w2f) {
    int i = blockIdx.x * blockDim.x + threadIdx.x;
    if (i < IN_DIM * HID) {
        int t8 = i & 7, lane = (i >> 3) & 63, jk = i >> 9;
        int kk = jk >> 3, jt = jk & 7, cc = lane & 15, qq = lane >> 4;
        int n = jt * 16 + cc, k = kk * 32 + qq * 8 + t8;
        w1f[i] = f2bf(W1[k * HID + n]);
    } else if (i < IN_DIM * HID + HID * OUTD) {
        int u = i - IN_DIM * HID;
        int t8 = u & 7, lane = (u >> 3) & 63, jk = u >> 9;
        int kk = jk >> 2, jt = jk & 3, cc = lane & 15, qq = lane >> 4;
        int n = jt * 16 + cc, k = kk * 32 + qq * 8 + t8;
        w2f[u] = f2bf(W2[k * OUTD + n]);
    }
}

// One 128-edge tile: GEMM1 (registers pre-staged) -> relu -> LDS -> GEMM2 -> store.
// If PREFETCH: issue next tile's x-gathers after GEMM1 (covered by GEMM2+epilogues)
// and next tile's edge_attr loads after GEMM2 MFMAs (covered by epilogue2+barrier+GEMM1).
template<bool XBF, bool PREFETCH>
__device__ __forceinline__ void tile_body(
    unsigned short* h,
    const float* __restrict__ x, const unsigned short* __restrict__ xbf,
    const float* __restrict__ ea,
    const float* __restrict__ b1, const float* __restrict__ b2,
    const unsigned short* __restrict__ w1f, const unsigned short* __restrict__ w2f,
    float* __restrict__ out,
    const int lane, const int wr, const int wc, const int c, const int q,
    const int (&eRow)[4], const int (&srcOff)[4], const int (&tgtOff)[4],
    v8s (&ax)[4][4], v4f (&eaf)[4][2],
    const int (&eRowN)[4], const int (&srcOffN)[4], const int (&tgtOffN)[4],
    v8s (&axN)[4][4], v4f (&eafN)[4][2])
{
    // ---- GEMM1: C1[128x128], wave quadrant 64x64 ----
    v4f acc[4][4] = {};
#pragma unroll
    for (int kk = 0; kk < 5; ++kk) {
        v8s a[4];
#pragma unroll
        for (int i = 0; i < 4; ++i) {
            if (kk < 4) {
                if constexpr (XBF) {
                    a[i] = ax[i][kk];
                } else {
                    const int off = (kk < 2 ? srcOff[i] : tgtOff[i]) + (kk & 1) * 32 + q * 8;
                    const v4f* p = (const v4f*)(x + off);
                    a[i] = cvt8v(p[0], p[1]);
                }
            } else {
                a[i] = cvt8v(eaf[i][0], eaf[i][1]);
            }
        }
        v8s b[4];
#pragma unroll
        for (int j = 0; j < 4; ++j)
            b[j] = *(const v8s*)(w1f + ((kk * 8 + wc * 4 + j) * 64 + lane) * 8);
#pragma unroll
        for (int i = 0; i < 4; ++i)
#pragma unroll
            for (int j = 0; j < 4; ++j)
                acc[i][j] = __builtin_amdgcn_mfma_f32_16x16x32_bf16(a[i], b[j], acc[i][j], 0, 0, 0);
    }

    // ---- epilogue1: h = relu(C1 + b1) -> bf16 LDS ----
#pragma unroll
    for (int j = 0; j < 4; ++j) {
        const float bias = b1[wc * 64 + j * 16 + c];
#pragma unroll
        for (int i = 0; i < 4; ++i) {
#pragma unroll
            for (int r = 0; r < 4; ++r) {
                float v = acc[i][j][r] + bias;
                v = v > 0.f ? v : 0.f;
                h[(wr * 64 + i * 16 + q * 4 + r) * H_STRIDE + wc * 64 + j * 16 + c] = f2bf(v);
            }
        }
    }
    __syncthreads();

    // ---- prefetch next tile's gathered x rows (regs now free; drained at next barrier) ----
    if constexpr (PREFETCH && XBF) {
#pragma unroll
        for (int i = 0; i < 4; ++i) {
            axN[i][0] = *(const v8s*)(xbf + srcOffN[i] + q * 8);
            axN[i][1] = *(const v8s*)(xbf + srcOffN[i] + 32 + q * 8);
            axN[i][2] = *(const v8s*)(xbf + tgtOffN[i] + q * 8);
            axN[i][3] = *(const v8s*)(xbf + tgtOffN[i] + 32 + q * 8);
        }
    }

    // ---- GEMM2: C2[128x64] = h * W2, wave does 64x32 ----
    v4f acc2[4][2] = {};
#pragma unroll
    for (int kk = 0; kk < 4; ++kk) {
        v8s a[4];
#pragma unroll
        for (int i = 0; i < 4; ++i)
            a[i] = *(const v8s*)(h + (wr * 64 + i * 16 + c) * H_STRIDE + kk * 32 + q * 8);
        v8s b[2];
#pragma unroll
        for (int j = 0; j < 2; ++j)
            b[j] = *(const v8s*)(w2f + ((kk * 4 + wc * 2 + j) * 64 + lane) * 8);
#pragma unroll
        for (int i = 0; i < 4; ++i)
#pragma unroll
            for (int j = 0; j < 2; ++j)
                acc2[i][j] = __builtin_amdgcn_mfma_f32_16x16x32_bf16(a[i], b[j], acc2[i][j], 0, 0, 0);
    }

    // ---- prefetch next tile's edge_attr (streaming, nontemporal) ----
    if constexpr (PREFETCH) {
#pragma unroll
        for (int i = 0; i < 4; ++i) {
            const v4f* p = (const v4f*)(ea + (long)eRowN[i] * ED + q * 8);
            eafN[i][0] = __builtin_nontemporal_load(p);
            eafN[i][1] = __builtin_nontemporal_load(p + 1);
        }
    }

    // ---- epilogue2: out = C2 + b2 (fp32, streaming stores) ----
#pragma unroll
    for (int j = 0; j < 2; ++j) {
        const float bias = b2[wc * 32 + j * 16 + c];
#pragma unroll
        for (int i = 0; i < 4; ++i) {
#pragma unroll
            for (int r = 0; r < 4; ++r) {
                const long e = (long)(eRow[i] - c + q * 4 + r);
                __builtin_nontemporal_store(acc2[i][j][r] + bias,
                                            out + e * OUTD + wc * 32 + j * 16 + c);
            }
        }
    }
}

template<bool XBF>
__global__ __launch_bounds__(256, 3) void edge_mlp(
    const float* __restrict__ x, const unsigned short* __restrict__ xbf,
    const float* __restrict__ ea,
    const float* __restrict__ b1, const float* __restrict__ b2,
    const int* __restrict__ eidx,
    const unsigned short* __restrict__ w1f, const unsigned short* __restrict__ w2f,
    float* __restrict__ out)
{
    __shared__ unsigned short h[TM * H_STRIDE];   // 34816 B

    const int tid = threadIdx.x, lane = tid & 63, w = tid >> 6;
    const int wr = w >> 1, wc = w & 1, c = lane & 15, q = lane >> 4;
    const int e0 = blockIdx.x * (2 * TM);

    // both tiles' eidx issued up-front: tile B's gather chain root latency is hidden
    int eRowA[4], srcOffA[4], tgtOffA[4], eRowB[4], srcOffB[4], tgtOffB[4];
#pragma unroll
    for (int i = 0; i < 4; ++i) {
        eRowA[i] = e0 + wr * 64 + i * 16 + c;
        eRowB[i] = eRowA[i] + TM;
        srcOffA[i] = __builtin_nontemporal_load(eidx + eRowA[i]) * ND;
        tgtOffA[i] = __builtin_nontemporal_load(eidx + E_TOTAL + eRowA[i]) * ND;
        srcOffB[i] = __builtin_nontemporal_load(eidx + eRowB[i]) * ND;
        tgtOffB[i] = __builtin_nontemporal_load(eidx + E_TOTAL + eRowB[i]) * ND;
    }

    v8s axA[4][4], axB[4][4];
    v4f eafA[4][2], eafB[4][2];

    // stage ALL of tile A's gathered operand rows before any MFMA (deep MLP)
    if constexpr (XBF) {
#pragma unroll
        for (int i = 0; i < 4; ++i) {
            axA[i][0] = *(const v8s*)(xbf + srcOffA[i] + q * 8);
            axA[i][1] = *(const v8s*)(xbf + srcOffA[i] + 32 + q * 8);
            axA[i][2] = *(const v8s*)(xbf + tgtOffA[i] + q * 8);
            axA[i][3] = *(const v8s*)(xbf + tgtOffA[i] + 32 + q * 8);
        }
    }
#pragma unroll
    for (int i = 0; i < 4; ++i) {
        const v4f* p = (const v4f*)(ea + (long)eRowA[i] * ED + q * 8);
        eafA[i][0] = __builtin_nontemporal_load(p);
        eafA[i][1] = __builtin_nontemporal_load(p + 1);
    }

    tile_body<XBF, true>(h, x, xbf, ea, b1, b2, w1f, w2f, out, lane, wr, wc, c, q,
                         eRowA, srcOffA, tgtOffA, axA, eafA,
                         eRowB, srcOffB, tgtOffB, axB, eafB);
    __syncthreads();   // tile A GEMM2 h-reads done before tile B h-writes
    tile_body<XBF, false>(h, x, xbf, ea, b1, b2, w1f, w2f, out, lane, wr, wc, c, q,
                          eRowB, srcOffB, tgtOffB, axB, eafB,
                          eRowB, srcOffB, tgtOffB, axB, eafB);
}

extern "C" void kernel_launch(void* const* d_in, const int* in_sizes, int n_in,
                              void* d_out, int out_size, void* d_ws, size_t ws_size,
                              hipStream_t stream) {
    const float* x  = (const float*)d_in[0];
    const float* ea = (const float*)d_in[1];
    const float* W1 = (const float*)d_in[2];
    const float* b1 = (const float*)d_in[3];
    const float* W2 = (const float*)d_in[4];
    const float* b2 = (const float*)d_in[5];
    const int* eidx = (const int*)d_in[6];
    float* out = (float*)d_out;

    const size_t nx = (size_t)N_NODES * ND;                          // 6.4M bf16
    const size_t need = (nx + IN_DIM * HID + HID * OUTD) * 2;        // ~12.86 MB
    const int nw = IN_DIM * HID + HID * OUTD;                        // 28672 weight elems
    const int grid = E_TOTAL / (2 * TM);                             // 6250 blocks, 2 tiles each

    if (ws_size >= need) {
        unsigned short* xbf = (unsigned short*)d_ws;
        unsigned short* w1f = xbf + nx;
        unsigned short* w2f = w1f + IN_DIM * HID;
        prep_x<<<(int)((nx + 255) / 256), 256, 0, stream>>>(x, xbf);
        prep_weights<<<(nw + 255) / 256, 256, 0, stream>>>(W1, W2, w1f, w2f);
        edge_mlp<true><<<grid, 256, 0, stream>>>(x, xbf, ea, b1, b2, eidx, w1f, w2f, out);
    } else {
        unsigned short* w1f = (unsigned short*)d_ws;
        unsigned short* w2f = w1f + IN_DIM * HID;
        prep_weights<<<(nw + 255) / 256, 256, 0, stream>>>(W1, W2, w1f, w2f);
        edge_mlp<false><<<grid, 256, 0, stream>>>(x, nullptr, ea, b1, b2, eidx, w1f, w2f, out);
    }
}